// Round 12
// baseline (1153.124 us; speedup 1.0000x reference)
//
#include <hip/hip_runtime.h>
#include <cstddef>
#include <cstdint>

typedef __attribute__((ext_vector_type(8))) _Float16 half8;
typedef __attribute__((ext_vector_type(4))) _Float16 half4;
typedef __attribute__((ext_vector_type(4))) float f32x4;
typedef _Float16 half_t;

#define NS 16
#define NN 32

// ---------------- workspace layout (bytes) ----------------
// h1p : f16 [n][s][64][66][32] x-padded   = 138412032   (ws)
// h2p : f16 [n][s][64][66][64] x-padded, chunk-swizzled = 276824064 (in d_out)
// h3  : f16 [s][n][c][y][x] pre-BN3       = 268435456   (ws)
static const size_t OFF_H1P = 0;
static const size_t OFF_H3  = 138412032ull;
static const size_t OFF_ZR1 = 138412032ull + 276824064ull; // 415236096
static const size_t OFF_ZR2 = OFF_ZR1 + 67584ull;       // 415303680
static const size_t OFF_WT1 = OFF_ZR2 + 135168ull;      // 415438848
static const size_t OFF_WT2 = OFF_WT1 + 55296ull;       // 415494144
static const size_t OFF_WT3 = OFF_WT2 + 589824ull;      // 416083968
static const size_t OFF_SUMS = OFF_WT3 + 1179648ull;    // 417263616
static const size_t OFF_PRM = OFF_SUMS + 20480ull;      // 417284096
static const size_t OFF_TH  = OFF_PRM + 30720ull;       // 417314816

static __device__ __forceinline__ half8 sr8(half8 v, half8 t) {
    half8 r = v + t;
    half8 z = {};
#if defined(__has_builtin) && __has_builtin(__builtin_elementwise_max)
    return __builtin_elementwise_max(r, z);
#else
#pragma unroll
    for (int j = 0; j < 8; ++j) r[j] = r[j] > (_Float16)0 ? r[j] : (_Float16)0;
    return r;
#endif
}

typedef __attribute__((address_space(1))) const void gas_t;
typedef __attribute__((address_space(3))) void las_t;
static __device__ __forceinline__ void gl16(const void* g, void* l) {
    __builtin_amdgcn_global_load_lds((gas_t*)g, (las_t*)l, 16, 0, 0);
}

// stage one 66x64ch row (8448 B) into ring slot (r+18)%9 via global_load_lds.
// each wave covers 66 chunks: 2 issues (64 lanes + 2 lanes). src pre-swizzled.
static __device__ __forceinline__ void stage_row3(const half_t* __restrict__ img,
                                                  const half_t* __restrict__ zrow,
                                                  char* smem, int r, int w, int lane) {
    const char* src = (const char*)(((unsigned)r < 64u) ? (img + (size_t)r * 4224) : zrow)
                      + (size_t)w * 1056;
    char* dst = smem + (size_t)((unsigned)(r + 18) % 9u) * 8448 + w * 1056;
    gl16(src + lane * 16, dst + lane * 16);
    if (lane < 2) gl16(src + 1024 + lane * 16, dst + 1024 + lane * 16);
}

// -------- conv1 weights: oc-contiguous f32 --------
__global__ __launch_bounds__(256) void transform1_k(
    const float* __restrict__ w1, float* __restrict__ wt1)
{
    int idx = blockIdx.x * 256 + threadIdx.x;
    if (idx >= 13824) return;
    int o = idx & 31, tap = (idx >> 5) % 9, ic = (idx / 288) % 3, s = idx / 864;
    wt1[idx] = w1[((s * 32 + o) * 3 + ic) * 9 + tap];
}

// -------- conv2/conv3 weights: ic-contiguous f16, BN scale of previous layer folded --------
__global__ __launch_bounds__(256) void wtrans2_k(
    const float* __restrict__ w2, const float* __restrict__ a1, half_t* __restrict__ wt2)
{
    int idx = blockIdx.x * 256 + threadIdx.x;
    if (idx >= 294912) return;
    int ic = idx & 31, oc = (idx >> 5) & 63, tap = (idx >> 11) % 9, s = idx / 18432;
    wt2[idx] = (half_t)(w2[((s * 64 + oc) * 32 + ic) * 9 + tap] * a1[s * 32 + ic]);
}

__global__ __launch_bounds__(256) void wtrans3_k(
    const float* __restrict__ w3, const float* __restrict__ a2, half_t* __restrict__ wt3)
{
    int idx = blockIdx.x * 256 + threadIdx.x;
    if (idx >= 589824) return;
    int ic = idx & 63, oc = (idx >> 6) & 63, tap = (idx >> 12) % 9, s = idx / 36864;
    wt3[idx] = (half_t)(w3[((s * 64 + oc) * 64 + ic) * 9 + tap] * a2[s * 64 + ic]);
}

// -------- conv1: 3->32 per seed, fp32 vector math, writes x-padded h1p (pre-BN) + stats --------
__global__ __launch_bounds__(256) void conv1_k(
    const float* __restrict__ x, const float* __restrict__ wt1,
    const float* __restrict__ b1, half_t* __restrict__ h1p,
    float* __restrict__ sums1)
{
    __shared__ float smem[8512];
    float* xt = smem;
    float* bounce = smem;
    float* statsl = smem + 8448;
    const int tile = blockIdx.x, s = blockIdx.y, n = blockIdx.z;
    const int tx = tile & 3, ty = tile >> 2, tid = threadIdx.x;

    for (int i = tid; i < 972; i += 256) {
        int ic = i / 324, rem = i - ic * 324;
        int py = rem / 18, px = rem - py * 18;
        int gy = ty * 16 + py - 1, gx = tx * 16 + px - 1;
        float v = 0.f;
        if ((unsigned)gy < 64u && (unsigned)gx < 64u)
            v = x[(size_t)(((s * NN + n) * 3 + ic) * 64 + gy) * 64 + gx];
        xt[i] = v;
    }
    if (tid < 64) statsl[tid] = 0.f;
    __syncthreads();

    const int px = tid & 15, py = tid >> 4;
    float acc[32];
#pragma unroll
    for (int o = 0; o < 32; ++o) acc[o] = 0.f;
#pragma unroll
    for (int ic = 0; ic < 3; ++ic)
#pragma unroll
        for (int ky = 0; ky < 3; ++ky)
#pragma unroll
            for (int kx = 0; kx < 3; ++kx) {
                float v = xt[ic * 324 + (py + ky) * 18 + px + kx];
                const float* wp = wt1 + ((s * 3 + ic) * 9 + ky * 3 + kx) * 32;
#pragma unroll
                for (int o = 0; o < 32; ++o) acc[o] = fmaf(wp[o], v, acc[o]);
            }
    const float* bp = b1 + s * 32;
#pragma unroll
    for (int o = 0; o < 32; ++o) acc[o] += bp[o];

    const int gy1 = ty * 16 + py, gxp = tx * 16 + px + 1;
    half8* dst = (half8*)(h1p + (size_t)(n * NS + s) * 135168 + (size_t)(gy1 * 66 + gxp) * 32);
#pragma unroll
    for (int k = 0; k < 4; ++k) {
        half8 v8;
#pragma unroll
        for (int j = 0; j < 8; ++j) v8[j] = (half_t)acc[k * 8 + j];
        dst[k] = v8;
    }
    __syncthreads();
#pragma unroll
    for (int o = 0; o < 32; ++o) bounce[tid * 33 + o] = acc[o];
    __syncthreads();
    {
        const int oc = tid & 31, grp = tid >> 5;
        float s1 = 0.f, s2 = 0.f;
#pragma unroll 4
        for (int jj = 0; jj < 32; ++jj) {
            float v = bounce[(grp * 32 + jj) * 33 + oc];
            s1 += v; s2 += v * v;
        }
        atomicAdd(&statsl[oc * 2], s1);
        atomicAdd(&statsl[oc * 2 + 1], s2);
    }
    __syncthreads();
    if (tid < 64)
        atomicAdd(&sums1[(s * 32 + (tid >> 1)) * 2 + (tid & 1)], statsl[tid]);
}

// -------- sums -> scale a, shift b, pre-act shift t = b/a (and f16 copy) --------
__global__ void bnparam_k(const float* __restrict__ sums, const float* __restrict__ g,
                          const float* __restrict__ be, float* __restrict__ a,
                          float* __restrict__ b, float* __restrict__ t,
                          half_t* __restrict__ th, int C)
{
    int ch = blockIdx.x * 256 + threadIdx.x;
    if (ch >= C) return;
    const float inv = 1.f / 131072.f;     // N*H*W = 32*64*64
    float mean = sums[ch * 2] * inv;
    float var = sums[ch * 2 + 1] * inv - mean * mean;
    float sc = g[ch] * rsqrtf(var + 1e-5f);
    a[ch] = sc;
    float bb = be[ch] - mean * sc;
    b[ch] = bb;
    float tt = bb / sc;
    t[ch] = tt;
    th[ch] = (half_t)tt;
}

// -------- fill pad columns + pad row with q = -(t+1); optional chunk swizzle --------
__global__ __launch_bounds__(256) void padfill_k(
    half_t* __restrict__ img, half_t* __restrict__ zrow, const float* __restrict__ t,
    int C, int c8shift, long imgstride, int rowstride, long tot_cols, long tot, int swz)
{
    long idx = (long)blockIdx.x * 256 + threadIdx.x;
    if (idx >= tot) return;
    const int nc8m = (1 << c8shift) - 1;
    if (idx < tot_cols) {
        int c8 = (int)idx & nc8m; long r = idx >> c8shift;
        int side = (int)r & 1; r >>= 1;
        int y = (int)r & 63; r >>= 6;
        int si = (int)(r & 15); int ni = (int)(r >> 4);
        half8 q;
#pragma unroll
        for (int j = 0; j < 8; ++j) q[j] = (half_t)(-(t[si * C + c8 * 8 + j] + 1.0f));
        int col = side ? 65 : 0;
        int off = swz ? ((c8 * 8) ^ ((col & 7) << 3)) : (c8 * 8);
        *(half8*)(img + (long)(ni * NS + si) * imgstride + (long)y * rowstride +
                  col * C + off) = q;
    } else {
        long r2 = idx - tot_cols;
        int c8 = (int)r2 & nc8m; r2 >>= c8shift;
        int xx = (int)(r2 % 66); int si = (int)(r2 / 66);
        half8 q;
#pragma unroll
        for (int j = 0; j < 8; ++j) q[j] = (half_t)(-(t[si * C + c8 * 8 + j] + 1.0f));
        int off = swz ? ((c8 * 8) ^ ((xx & 7) << 3)) : (c8 * 8);
        *(half8*)(zrow + ((long)(si * 66 + xx)) * C + off) = q;
    }
}

// ======== conv2 (R4 version): 16x16 tile, 256 thr, LDS A-tile + 1-deep B prefetch ========
__device__ __forceinline__ void loadB2(half8 bf[4], const half_t* wb, int tap, int l15, int g) {
#pragma unroll
    for (int nt = 0; nt < 4; ++nt)
        bf[nt] = *(const half8*)(wb + (tap * 64 + nt * 16 + l15) * 32 + g * 8);
}

__device__ __forceinline__ void comp2(f32x4 acc[4][4], const half8 bf[4], const char* smem,
                                      int tap, int wv, int l15, int g) {
    const int ky = tap / 3, kx = tap - ky * 3;
#pragma unroll
    for (int mt = 0; mt < 4; ++mt) {
        int p = (wv * 4 + mt + ky) * 18 + l15 + kx;
        half8 av = *(const half8*)(smem + p * 80 + g * 16);
#pragma unroll
        for (int nt = 0; nt < 4; ++nt)
            acc[mt][nt] = __builtin_amdgcn_mfma_f32_16x16x32_f16(av, bf[nt], acc[mt][nt], 0, 0, 0);
    }
}

__global__ __launch_bounds__(256, 3) void conv2_k(
    const half_t* __restrict__ h1p, const half_t* __restrict__ zr1,
    const half_t* __restrict__ wt2, const float* __restrict__ b2,
    const half_t* __restrict__ th1, half_t* __restrict__ h2p,
    float* __restrict__ sums2)
{
    __shared__ __align__(16) char smem[37376];  // A-tile (25920) / obuf (36864) union; statsl @36864
    float* statsl = (float*)(smem + 36864);
    const int tile = blockIdx.x, s = blockIdx.y, n = blockIdx.z;
    const int tx = tile & 3, ty = tile >> 2, tid = threadIdx.x;
    const int l = tid & 63, wv = tid >> 6, l15 = l & 15, g = l >> 4;
    if (tid < 128) statsl[tid] = 0.f;

    const half_t* wb = wt2 + (size_t)s * 18432;
    half8 bfa[4], bfb[4];
    loadB2(bfa, wb, 0, l15, g);

    // stage 18x18x32 A-tile, 80B pixel stride, BN1-shift+relu applied
    const half_t* img = h1p + (size_t)(n * NS + s) * 135168;
    const half_t* zrow = zr1 + s * 2112;
    const int j = tid & 3;
    const half8 tshj = *(const half8*)(th1 + s * 32 + j * 8);
    for (int i = tid; i < 1296; i += 256) {
        int p = i >> 2;
        int py = p / 18, pxx = p - py * 18;
        int gy = ty * 16 + py - 1;
        const half_t* rp = ((unsigned)gy < 64u) ? (img + (size_t)gy * 2112) : zrow;
        half8 v = sr8(*(const half8*)(rp + (tx * 16 + pxx) * 32 + j * 8), tshj);
        *(half8*)(smem + p * 80 + j * 16) = v;
    }
    __syncthreads();

    f32x4 acc[4][4];
#pragma unroll
    for (int mt = 0; mt < 4; ++mt)
#pragma unroll
        for (int nt = 0; nt < 4; ++nt) acc[mt][nt] = (f32x4){0.f, 0.f, 0.f, 0.f};

#pragma unroll
    for (int tap = 0; tap < 9; ++tap) {
        if (tap & 1) {
            if (tap < 8) loadB2(bfa, wb, tap + 1, l15, g);
            comp2(acc, bfb, smem, tap, wv, l15, g);
        } else {
            if (tap < 8) loadB2(bfb, wb, tap + 1, l15, g);
            comp2(acc, bfa, smem, tap, wv, l15, g);
        }
    }

    // bias + per-channel stats
    float s1a[4], s2a[4];
#pragma unroll
    for (int nt = 0; nt < 4; ++nt) {
        float bias = b2[s * 64 + nt * 16 + l15];
        float s1 = 0.f, s2 = 0.f;
#pragma unroll
        for (int mt = 0; mt < 4; ++mt)
#pragma unroll
            for (int r = 0; r < 4; ++r) {
                float v = acc[mt][nt][r] + bias;
                acc[mt][nt][r] = v;
                s1 += v; s2 += v * v;
            }
        s1 += __shfl_xor(s1, 16); s1 += __shfl_xor(s1, 32);
        s2 += __shfl_xor(s2, 16); s2 += __shfl_xor(s2, 32);
        s1a[nt] = s1; s2a[nt] = s2;
    }
    if (l < 16) {
#pragma unroll
        for (int nt = 0; nt < 4; ++nt) {
            atomicAdd(&statsl[(nt * 16 + l15) * 2], s1a[nt]);
            atomicAdd(&statsl[(nt * 16 + l15) * 2 + 1], s2a[nt]);
        }
    }
    __syncthreads();                      // A reads + stats done -> reuse smem as obuf

    half_t* obuf = (half_t*)smem;         // [256 px][72]
#pragma unroll
    for (int mt = 0; mt < 4; ++mt)
#pragma unroll
        for (int nt = 0; nt < 4; ++nt)
#pragma unroll
            for (int r = 0; r < 4; ++r)
                obuf[((wv * 4 + mt) * 16 + g * 4 + r) * 72 + nt * 16 + l15] = (half_t)acc[mt][nt][r];
    __syncthreads();

    // copy-out with chunk swizzle: chunk cc of pixel xp at half-offset (cc*8)^((xp&7)<<3)
    half_t* img2 = h2p + (size_t)(n * NS + s) * 270336;
    for (int i = tid; i < 2048; i += 256) {
        int p = i >> 3, cc = i & 7;
        int y = ty * 16 + (p >> 4), xp = tx * 16 + (p & 15) + 1;
        *(half8*)(img2 + (size_t)y * 4224 + xp * 64 + ((cc * 8) ^ ((xp & 7) << 3))) =
            *(const half8*)(obuf + p * 72 + cc * 8);
    }
    if (tid < 128)
        atomicAdd(&sums2[(s * 64 + (tid >> 1)) * 2 + (tid & 1)], statsl[tid]);
}

// ======== conv3: 64x16 strip, 9-slot ring, global_load_lds + counted vmcnt, 6-deep weights ====
__global__ __launch_bounds__(512, 4) void conv3_k(
    const half_t* __restrict__ h2p, const half_t* __restrict__ zr2,
    const half_t* __restrict__ wt3, const float* __restrict__ b3,
    const half_t* __restrict__ th2, half_t* __restrict__ h3,
    float* __restrict__ sums3)
{
    __shared__ __align__(16) char smem[76544];  // 9 slots * 8448 = 76032 + statsl
    float* statsl = (float*)(smem + 76032);
    const int strip = blockIdx.x, s = blockIdx.y, n = blockIdx.z;
    const int tid = threadIdx.x;
    const int l = tid & 63, w = tid >> 6, l15 = l & 15, g = l >> 4;
    const int wy = w & 3, och = w >> 2;
    const int yb = strip * 16;
    if (tid < 128) statsl[tid] = 0.f;

    const half_t* img = h2p + (size_t)(n * NS + s) * 270336;
    const half_t* zrow = zr2 + s * 4224;
    const half_t* wb = wt3 + (size_t)s * 36864;
    const half8 tsh0 = *(const half8*)(th2 + s * 64 + g * 8);
    const half8 tsh1 = *(const half8*)(th2 + s * 64 + 32 + g * 8);

    const int UT[18] = {0,1,2,0,1,2, 3,4,5,6,7,8, 3,4,5,6,7,8};
    const int UK[18] = {0,0,0,1,1,1, 0,0,0,0,0,0, 1,1,1,1,1,1};
    half8 wAa,wAb,wBa,wBb,wCa,wCb,wDa,wDb,wEa,wEb,wFa,wFb;
#define LWQ(W, U) { \
    W##a = *(const half8*)(wb + (UT[U]*64 + och*32 + l15)*64 + UK[U]*32 + g*8); \
    W##b = *(const half8*)(wb + (UT[U]*64 + och*32 + 16 + l15)*64 + UK[U]*32 + g*8); }
#define CS(W, U) { \
    const char* rp_ = (UT[U] < 3) ? rp0 : (UT[U] < 6) ? rp1 : rp2; \
    const int kx_ = UT[U] % 3; \
    const half8 tsh_ = UK[U] ? tsh1 : tsh0; \
    _Pragma("unroll") \
    for (int mt = 0; mt < 4; ++mt) { \
        int px = mt*16 + l15 + kx_; \
        int sw = (px & 7) << 4; \
        half8 a_ = sr8(*(const half8*)(rp_ + px*128 + ((UK[U]*64 + g*16) ^ sw)), tsh_); \
        acc[mt][0] = __builtin_amdgcn_mfma_f32_16x16x32_f16(a_, W##a, acc[mt][0], 0, 0, 0); \
        acc[mt][1] = __builtin_amdgcn_mfma_f32_16x16x32_f16(a_, W##b, acc[mt][1], 0, 0, 0); \
    } }

    // weight preload steps 0..5 (BEFORE stage DMAs: in-order vmcnt retirement
    // then doesn't force DMA completion until step-6's consume)
    LWQ(wA,0) LWQ(wB,1) LWQ(wC,2) LWQ(wD,3) LWQ(wE,4) LWQ(wF,5)
    __builtin_amdgcn_sched_barrier(0);

    // prologue: stage rows yb-1 .. yb+7 (9 rows; 18 DMA issues/wave)
    for (int r = yb - 1; r <= yb + 7; ++r)
        stage_row3(img, zrow, smem, r, w, l);
    __builtin_amdgcn_sched_barrier(0);
    asm volatile("s_waitcnt vmcnt(6)" ::: "memory");   // rows yb-1..yb+4 landed; yb+5..7 in flight
    __builtin_amdgcn_s_barrier();
    __builtin_amdgcn_sched_barrier(0);

    const float bias0 = b3[s * 64 + och * 32 + l15];
    const float bias1 = b3[s * 64 + och * 32 + 16 + l15];
    float s10 = 0.f, s20 = 0.f, s11 = 0.f, s21 = 0.f;
    half_t* hb = h3 + (size_t)((s * NN + n) * 64) * 4096;

#pragma unroll 1
    for (int t = 0; t < 4; ++t) {
        const int rb = yb + 4 * t;
        const int r0 = rb + wy - 1;
        const char* rp0 = smem + (size_t)((unsigned)(r0 + 18) % 9u) * 8448;
        const char* rp1 = smem + (size_t)((unsigned)(r0 + 19) % 9u) * 8448;
        const char* rp2 = smem + (size_t)((unsigned)(r0 + 20) % 9u) * 8448;

        f32x4 acc[4][2];
#pragma unroll
        for (int mt = 0; mt < 4; ++mt)
#pragma unroll
            for (int nt = 0; nt < 2; ++nt) acc[mt][nt] = (f32x4){0.f, 0.f, 0.f, 0.f};

        // 18-step chain; slot u%6, refill u+6 (refills at u>=12 preload next iter's 0..5)
        CS(wA,0)   LWQ(wA,6)
        CS(wB,1)   LWQ(wB,7)
        CS(wC,2)   LWQ(wC,8)
        CS(wD,3)   LWQ(wD,9)
        CS(wE,4)   LWQ(wE,10)
        CS(wF,5)   LWQ(wF,11)
        CS(wA,6)   LWQ(wA,12)
        CS(wB,7)   LWQ(wB,13)
        CS(wC,8)   LWQ(wC,14)
        CS(wD,9)   LWQ(wD,15)
        CS(wE,10)  LWQ(wE,16)
        CS(wF,11)  LWQ(wF,17)
        CS(wA,12)  LWQ(wA,0)
        CS(wB,13)  LWQ(wB,1)
        CS(wC,14)  LWQ(wC,2)
        CS(wD,15)  LWQ(wD,3)
        CS(wE,16)  LWQ(wE,4)
        CS(wF,17)  LWQ(wF,5)

        // epilogue: bias + stats + coalesced f16 store (pre-BN3)
        const int gy = rb + wy;
#pragma unroll
        for (int mt = 0; mt < 4; ++mt)
#pragma unroll
            for (int nt = 0; nt < 2; ++nt) {
                int c = och * 32 + nt * 16 + l15;
                float bias = nt ? bias1 : bias0;
                half4 hv;
#pragma unroll
                for (int r = 0; r < 4; ++r) {
                    float vv = acc[mt][nt][r] + bias;
                    hv[r] = (half_t)vv;
                    if (nt) { s11 += vv; s21 += vv * vv; } else { s10 += vv; s20 += vv * vv; }
                }
                *(half4*)(hb + (size_t)c * 4096 + gy * 64 + mt * 16 + g * 4) = hv;
            }

        __builtin_amdgcn_sched_barrier(0);
        asm volatile("s_waitcnt lgkmcnt(0)" ::: "memory");
        __builtin_amdgcn_s_barrier();            // rows rb-1..rb+2 now dead
        __builtin_amdgcn_sched_barrier(0);
        if (t < 3) {
            stage_row3(img, zrow, smem, rb + 8, w, l);       // into slot of dead rb-1
            if (t < 2) {
                stage_row3(img, zrow, smem, rb + 9, w, l);   // slots of dead rb..rb+2
                stage_row3(img, zrow, smem, rb + 10, w, l);
                stage_row3(img, zrow, smem, rb + 11, w, l);
            }
            __builtin_amdgcn_sched_barrier(0);
            if (t < 2) asm volatile("s_waitcnt vmcnt(6)" ::: "memory"); // rb+8 landed; rb+9..11 fly
            else       asm volatile("s_waitcnt vmcnt(0)" ::: "memory");
            __builtin_amdgcn_s_barrier();
            __builtin_amdgcn_sched_barrier(0);
        }
    }
#undef CS
#undef LWQ

    // stats flush
    s10 += __shfl_xor(s10, 16); s10 += __shfl_xor(s10, 32);
    s20 += __shfl_xor(s20, 16); s20 += __shfl_xor(s20, 32);
    s11 += __shfl_xor(s11, 16); s11 += __shfl_xor(s11, 32);
    s21 += __shfl_xor(s21, 16); s21 += __shfl_xor(s21, 32);
    if (l < 16) {
        atomicAdd(&statsl[(och * 32 + l15) * 2], s10);
        atomicAdd(&statsl[(och * 32 + l15) * 2 + 1], s20);
        atomicAdd(&statsl[(och * 32 + 16 + l15) * 2], s11);
        atomicAdd(&statsl[(och * 32 + 16 + l15) * 2 + 1], s21);
    }
    __syncthreads();
    if (tid < 128)
        atomicAdd(&sums3[(s * 64 + (tid >> 1)) * 2 + (tid & 1)], statsl[tid]);
}

// -------- final: read f16 pre-BN3 (half8), apply BN3+ReLU, write fp32 d_out --------
// 2^27 elements total / 8 per iter = 16777216 iterations
__global__ __launch_bounds__(256) void final_k(float* __restrict__ out,
                                               const half_t* __restrict__ h3,
                                               const float* __restrict__ a3,
                                               const float* __restrict__ b3p)
{
    const size_t stride = (size_t)gridDim.x * 256;
    for (size_t i = (size_t)blockIdx.x * 256 + threadIdx.x; i < 16777216ull; i += stride) {
        size_t e = i * 8;
        int ch = (int)((e >> 12) & 63) + (int)(e >> 23) * 64; // c + s*64
        float sc = a3[ch], sh = b3p[ch];
        half8 hv = *(const half8*)(h3 + e);
        f32x4 v0, v1;
#pragma unroll
        for (int r = 0; r < 4; ++r) {
            v0[r] = fmaxf(fmaf(sc, (float)hv[r], sh), 0.f);
            v1[r] = fmaxf(fmaf(sc, (float)hv[r + 4], sh), 0.f);
        }
        *(f32x4*)(out + e) = v0;
        *(f32x4*)(out + e + 4) = v1;
    }
}

extern "C" void kernel_launch(void* const* d_in, const int* in_sizes, int n_in,
                              void* d_out, int out_size, void* d_ws, size_t ws_size,
                              hipStream_t stream)
{
    const float* x   = (const float*)d_in[0];
    const float* w1  = (const float*)d_in[1];
    const float* b1  = (const float*)d_in[2];
    const float* g1  = (const float*)d_in[3];
    const float* be1 = (const float*)d_in[4];
    const float* w2  = (const float*)d_in[5];
    const float* b2  = (const float*)d_in[6];
    const float* g2  = (const float*)d_in[7];
    const float* be2 = (const float*)d_in[8];
    const float* w3  = (const float*)d_in[9];
    const float* b3  = (const float*)d_in[10];
    const float* g3  = (const float*)d_in[11];
    const float* be3 = (const float*)d_in[12];

    char* ws = (char*)d_ws;
    half_t* h1p = (half_t*)(ws + OFF_H1P);
    half_t* h2p = (half_t*)d_out;              // h2 lives in d_out (277MB <= 512MB)
    half_t* h3  = (half_t*)(ws + OFF_H3);      // f16 pre-BN3 output
    half_t* zr1 = (half_t*)(ws + OFF_ZR1);
    half_t* zr2 = (half_t*)(ws + OFF_ZR2);
    float*  wt1 = (float*)(ws + OFF_WT1);
    half_t* wt2 = (half_t*)(ws + OFF_WT2);
    half_t* wt3 = (half_t*)(ws + OFF_WT3);
    float*  sums = (float*)(ws + OFF_SUMS);
    float *s1v = sums, *s2v = sums + 1024, *s3v = sums + 3072;
    float*  prm = (float*)(ws + OFF_PRM);
    float *a1 = prm,        *b1p = prm + 512,  *t1 = prm + 1024;
    float *a2 = prm + 1536, *b2p = prm + 2560, *t2 = prm + 3584;
    float *a3 = prm + 4608, *b3p = prm + 5632, *t3 = prm + 6656;
    half_t* th = (half_t*)(ws + OFF_TH);
    half_t *th1 = th, *th2 = th + 512, *th3 = th + 1536;
    float* out = (float*)d_out;

    hipMemsetAsync(ws + OFF_SUMS, 0, 20480, stream);
    transform1_k<<<54, 256, 0, stream>>>(w1, wt1);
    dim3 grid1(16, 16, 32); // (tile, seed, sample)
    conv1_k<<<grid1, 256, 0, stream>>>(x, wt1, b1, h1p, s1v);
    bnparam_k<<<2, 256, 0, stream>>>(s1v, g1, be1, a1, b1p, t1, th1, 512);
    padfill_k<<<1041, 256, 0, stream>>>(h1p, zr1, t1, 32, 2, 135168L, 2112, 262144L, 266368L, 0);
    wtrans2_k<<<1152, 256, 0, stream>>>(w2, a1, wt2);
    conv2_k<<<grid1, 256, 0, stream>>>(h1p, zr1, wt2, b2, th1, h2p, s2v);
    bnparam_k<<<4, 256, 0, stream>>>(s2v, g2, be2, a2, b2p, t2, th2, 1024);
    padfill_k<<<2081, 256, 0, stream>>>(h2p, zr2, t2, 64, 3, 270336L, 4224, 524288L, 532736L, 1);
    wtrans3_k<<<2304, 256, 0, stream>>>(w3, a2, wt3);
    dim3 grid3(4, 16, 32); // (strip, seed, sample)
    conv3_k<<<grid3, 512, 0, stream>>>(h2p, zr2, wt3, b3, th2, h3, s3v);
    bnparam_k<<<4, 256, 0, stream>>>(s3v, g3, be3, a3, b3p, t3, th3, 1024);
    final_k<<<4096, 256, 0, stream>>>(out, h3, a3, b3p);
}

// Round 13
// 826.188 us; speedup vs baseline: 1.3957x; 1.3957x over previous
//
#include <hip/hip_runtime.h>
#include <cstddef>
#include <cstdint>

typedef __attribute__((ext_vector_type(8))) _Float16 half8;
typedef __attribute__((ext_vector_type(4))) _Float16 half4;
typedef __attribute__((ext_vector_type(4))) float f32x4;
typedef _Float16 half_t;

#define NS 16
#define NN 32

// ---------------- workspace layout (bytes) ----------------
// h1p : f16 [n][s][64][66][32] x-padded   = 138412032   (ws)
// h2p : f16 [n][s][64][66][64] x-padded   = 276824064   (lives in d_out!)
// h3  : f16 [s][n][c][y][x] pre-BN3       = 268435456   (ws)
static const size_t OFF_H1P = 0;
static const size_t OFF_H3  = 138412032ull;
static const size_t OFF_ZR1 = 138412032ull + 276824064ull; // 415236096
static const size_t OFF_ZR2 = OFF_ZR1 + 67584ull;       // 415303680
static const size_t OFF_WT1 = OFF_ZR2 + 135168ull;      // 415438848
static const size_t OFF_WT2 = OFF_WT1 + 55296ull;       // 415494144
static const size_t OFF_WT3 = OFF_WT2 + 589824ull;      // 416083968
static const size_t OFF_SUMS = OFF_WT3 + 1179648ull;    // 417263616
static const size_t OFF_PRM = OFF_SUMS + 20480ull;      // 417284096
static const size_t OFF_TH  = OFF_PRM + 30720ull;       // 417314816

static __device__ __forceinline__ half8 sr8(half8 v, half8 t) {
    half8 r = v + t;
    half8 z = {};
#if defined(__has_builtin) && __has_builtin(__builtin_elementwise_max)
    return __builtin_elementwise_max(r, z);
#else
#pragma unroll
    for (int j = 0; j < 8; ++j) r[j] = r[j] > (_Float16)0 ? r[j] : (_Float16)0;
    return r;
#endif
}

// -------- conv1 weights: oc-contiguous f32 --------
__global__ __launch_bounds__(256) void transform1_k(
    const float* __restrict__ w1, float* __restrict__ wt1)
{
    int idx = blockIdx.x * 256 + threadIdx.x;
    if (idx >= 13824) return;
    int o = idx & 31, tap = (idx >> 5) % 9, ic = (idx / 288) % 3, s = idx / 864;
    wt1[idx] = w1[((s * 32 + o) * 3 + ic) * 9 + tap];
}

// -------- conv2/conv3 weights: ic-contiguous f16, BN scale of previous layer folded --------
__global__ __launch_bounds__(256) void wtrans2_k(
    const float* __restrict__ w2, const float* __restrict__ a1, half_t* __restrict__ wt2)
{
    int idx = blockIdx.x * 256 + threadIdx.x;
    if (idx >= 294912) return;
    int ic = idx & 31, oc = (idx >> 5) & 63, tap = (idx >> 11) % 9, s = idx / 18432;
    wt2[idx] = (half_t)(w2[((s * 64 + oc) * 32 + ic) * 9 + tap] * a1[s * 32 + ic]);
}

__global__ __launch_bounds__(256) void wtrans3_k(
    const float* __restrict__ w3, const float* __restrict__ a2, half_t* __restrict__ wt3)
{
    int idx = blockIdx.x * 256 + threadIdx.x;
    if (idx >= 589824) return;
    int ic = idx & 63, oc = (idx >> 6) & 63, tap = (idx >> 12) % 9, s = idx / 36864;
    wt3[idx] = (half_t)(w3[((s * 64 + oc) * 64 + ic) * 9 + tap] * a2[s * 64 + ic]);
}

// -------- conv1: 3->32 per seed, fp32 vector math, writes x-padded h1p (pre-BN) + stats --------
__global__ __launch_bounds__(256) void conv1_k(
    const float* __restrict__ x, const float* __restrict__ wt1,
    const float* __restrict__ b1, half_t* __restrict__ h1p,
    float* __restrict__ sums1)
{
    __shared__ float smem[8512];
    float* xt = smem;
    float* bounce = smem;
    float* statsl = smem + 8448;
    const int tile = blockIdx.x, s = blockIdx.y, n = blockIdx.z;
    const int tx = tile & 3, ty = tile >> 2, tid = threadIdx.x;

    for (int i = tid; i < 972; i += 256) {
        int ic = i / 324, rem = i - ic * 324;
        int py = rem / 18, px = rem - py * 18;
        int gy = ty * 16 + py - 1, gx = tx * 16 + px - 1;
        float v = 0.f;
        if ((unsigned)gy < 64u && (unsigned)gx < 64u)
            v = x[(size_t)(((s * NN + n) * 3 + ic) * 64 + gy) * 64 + gx];
        xt[i] = v;
    }
    if (tid < 64) statsl[tid] = 0.f;
    __syncthreads();

    const int px = tid & 15, py = tid >> 4;
    float acc[32];
#pragma unroll
    for (int o = 0; o < 32; ++o) acc[o] = 0.f;
#pragma unroll
    for (int ic = 0; ic < 3; ++ic)
#pragma unroll
        for (int ky = 0; ky < 3; ++ky)
#pragma unroll
            for (int kx = 0; kx < 3; ++kx) {
                float v = xt[ic * 324 + (py + ky) * 18 + px + kx];
                const float* wp = wt1 + ((s * 3 + ic) * 9 + ky * 3 + kx) * 32;
#pragma unroll
                for (int o = 0; o < 32; ++o) acc[o] = fmaf(wp[o], v, acc[o]);
            }
    const float* bp = b1 + s * 32;
#pragma unroll
    for (int o = 0; o < 32; ++o) acc[o] += bp[o];

    const int gy1 = ty * 16 + py, gxp = tx * 16 + px + 1;
    half8* dst = (half8*)(h1p + (size_t)(n * NS + s) * 135168 + (size_t)(gy1 * 66 + gxp) * 32);
#pragma unroll
    for (int k = 0; k < 4; ++k) {
        half8 v8;
#pragma unroll
        for (int j = 0; j < 8; ++j) v8[j] = (half_t)acc[k * 8 + j];
        dst[k] = v8;
    }
    __syncthreads();
#pragma unroll
    for (int o = 0; o < 32; ++o) bounce[tid * 33 + o] = acc[o];
    __syncthreads();
    {
        const int oc = tid & 31, grp = tid >> 5;
        float s1 = 0.f, s2 = 0.f;
#pragma unroll 4
        for (int jj = 0; jj < 32; ++jj) {
            float v = bounce[(grp * 32 + jj) * 33 + oc];
            s1 += v; s2 += v * v;
        }
        atomicAdd(&statsl[oc * 2], s1);
        atomicAdd(&statsl[oc * 2 + 1], s2);
    }
    __syncthreads();
    if (tid < 64)
        atomicAdd(&sums1[(s * 32 + (tid >> 1)) * 2 + (tid & 1)], statsl[tid]);
}

// -------- sums -> scale a, shift b, pre-act shift t = b/a (and f16 copy) --------
__global__ void bnparam_k(const float* __restrict__ sums, const float* __restrict__ g,
                          const float* __restrict__ be, float* __restrict__ a,
                          float* __restrict__ b, float* __restrict__ t,
                          half_t* __restrict__ th, int C)
{
    int ch = blockIdx.x * 256 + threadIdx.x;
    if (ch >= C) return;
    const float inv = 1.f / 131072.f;     // N*H*W = 32*64*64
    float mean = sums[ch * 2] * inv;
    float var = sums[ch * 2 + 1] * inv - mean * mean;
    float sc = g[ch] * rsqrtf(var + 1e-5f);
    a[ch] = sc;
    float bb = be[ch] - mean * sc;
    b[ch] = bb;
    float tt = bb / sc;
    t[ch] = tt;
    th[ch] = (half_t)tt;
}

// -------- fill pad columns + pad row with q = -(t+1), so relu(q + t) == 0 --------
__global__ __launch_bounds__(256) void padfill_k(
    half_t* __restrict__ img, half_t* __restrict__ zrow, const float* __restrict__ t,
    int C, int c8shift, long imgstride, int rowstride, long tot_cols, long tot)
{
    long idx = (long)blockIdx.x * 256 + threadIdx.x;
    if (idx >= tot) return;
    const int nc8m = (1 << c8shift) - 1;
    if (idx < tot_cols) {
        int c8 = (int)idx & nc8m; long r = idx >> c8shift;
        int side = (int)r & 1; r >>= 1;
        int y = (int)r & 63; r >>= 6;
        int si = (int)(r & 15); int ni = (int)(r >> 4);
        half8 q;
#pragma unroll
        for (int j = 0; j < 8; ++j) q[j] = (half_t)(-(t[si * C + c8 * 8 + j] + 1.0f));
        *(half8*)(img + (long)(ni * NS + si) * imgstride + (long)y * rowstride +
                  (side ? 65 : 0) * C + c8 * 8) = q;
    } else {
        long r2 = idx - tot_cols;
        int c8 = (int)r2 & nc8m; r2 >>= c8shift;
        int xx = (int)(r2 % 66); int si = (int)(r2 / 66);
        half8 q;
#pragma unroll
        for (int j = 0; j < 8; ++j) q[j] = (half_t)(-(t[si * C + c8 * 8 + j] + 1.0f));
        *(half8*)(zrow + ((long)(si * 66 + xx)) * C + c8 * 8) = q;
    }
}

// ======== conv2 (R4 version): 16x16 tile, 256 thr, LDS A-tile + 1-deep B prefetch ========
__device__ __forceinline__ void loadB2(half8 bf[4], const half_t* wb, int tap, int l15, int g) {
#pragma unroll
    for (int nt = 0; nt < 4; ++nt)
        bf[nt] = *(const half8*)(wb + (tap * 64 + nt * 16 + l15) * 32 + g * 8);
}

__device__ __forceinline__ void comp2(f32x4 acc[4][4], const half8 bf[4], const char* smem,
                                      int tap, int wv, int l15, int g) {
    const int ky = tap / 3, kx = tap - ky * 3;
#pragma unroll
    for (int mt = 0; mt < 4; ++mt) {
        int p = (wv * 4 + mt + ky) * 18 + l15 + kx;
        half8 av = *(const half8*)(smem + p * 80 + g * 16);
#pragma unroll
        for (int nt = 0; nt < 4; ++nt)
            acc[mt][nt] = __builtin_amdgcn_mfma_f32_16x16x32_f16(av, bf[nt], acc[mt][nt], 0, 0, 0);
    }
}

__global__ __launch_bounds__(256, 3) void conv2_k(
    const half_t* __restrict__ h1p, const half_t* __restrict__ zr1,
    const half_t* __restrict__ wt2, const float* __restrict__ b2,
    const half_t* __restrict__ th1, half_t* __restrict__ h2p,
    float* __restrict__ sums2)
{
    __shared__ __align__(16) char smem[37376];  // A-tile (25920) / obuf (36864) union; statsl @36864
    float* statsl = (float*)(smem + 36864);
    const int tile = blockIdx.x, s = blockIdx.y, n = blockIdx.z;
    const int tx = tile & 3, ty = tile >> 2, tid = threadIdx.x;
    const int l = tid & 63, wv = tid >> 6, l15 = l & 15, g = l >> 4;
    if (tid < 128) statsl[tid] = 0.f;

    const half_t* wb = wt2 + (size_t)s * 18432;
    half8 bfa[4], bfb[4];
    loadB2(bfa, wb, 0, l15, g);

    // stage 18x18x32 A-tile, 80B pixel stride, BN1-shift+relu applied
    const half_t* img = h1p + (size_t)(n * NS + s) * 135168;
    const half_t* zrow = zr1 + s * 2112;
    const int j = tid & 3;
    const half8 tshj = *(const half8*)(th1 + s * 32 + j * 8);
    for (int i = tid; i < 1296; i += 256) {
        int p = i >> 2;
        int py = p / 18, pxx = p - py * 18;
        int gy = ty * 16 + py - 1;
        const half_t* rp = ((unsigned)gy < 64u) ? (img + (size_t)gy * 2112) : zrow;
        half8 v = sr8(*(const half8*)(rp + (tx * 16 + pxx) * 32 + j * 8), tshj);
        *(half8*)(smem + p * 80 + j * 16) = v;
    }
    __syncthreads();

    f32x4 acc[4][4];
#pragma unroll
    for (int mt = 0; mt < 4; ++mt)
#pragma unroll
        for (int nt = 0; nt < 4; ++nt) acc[mt][nt] = (f32x4){0.f, 0.f, 0.f, 0.f};

#pragma unroll
    for (int tap = 0; tap < 9; ++tap) {
        if (tap & 1) {
            if (tap < 8) loadB2(bfa, wb, tap + 1, l15, g);
            comp2(acc, bfb, smem, tap, wv, l15, g);
        } else {
            if (tap < 8) loadB2(bfb, wb, tap + 1, l15, g);
            comp2(acc, bfa, smem, tap, wv, l15, g);
        }
    }

    // bias + per-channel stats
    float s1a[4], s2a[4];
#pragma unroll
    for (int nt = 0; nt < 4; ++nt) {
        float bias = b2[s * 64 + nt * 16 + l15];
        float s1 = 0.f, s2 = 0.f;
#pragma unroll
        for (int mt = 0; mt < 4; ++mt)
#pragma unroll
            for (int r = 0; r < 4; ++r) {
                float v = acc[mt][nt][r] + bias;
                acc[mt][nt][r] = v;
                s1 += v; s2 += v * v;
            }
        s1 += __shfl_xor(s1, 16); s1 += __shfl_xor(s1, 32);
        s2 += __shfl_xor(s2, 16); s2 += __shfl_xor(s2, 32);
        s1a[nt] = s1; s2a[nt] = s2;
    }
    if (l < 16) {
#pragma unroll
        for (int nt = 0; nt < 4; ++nt) {
            atomicAdd(&statsl[(nt * 16 + l15) * 2], s1a[nt]);
            atomicAdd(&statsl[(nt * 16 + l15) * 2 + 1], s2a[nt]);
        }
    }
    __syncthreads();                      // A reads + stats done -> reuse smem as obuf

    half_t* obuf = (half_t*)smem;         // [256 px][72]
#pragma unroll
    for (int mt = 0; mt < 4; ++mt)
#pragma unroll
        for (int nt = 0; nt < 4; ++nt)
#pragma unroll
            for (int r = 0; r < 4; ++r)
                obuf[((wv * 4 + mt) * 16 + g * 4 + r) * 72 + nt * 16 + l15] = (half_t)acc[mt][nt][r];
    __syncthreads();

    half_t* img2 = h2p + (size_t)(n * NS + s) * 270336;
    for (int i = tid; i < 2048; i += 256) {
        int p = i >> 3, cc = i & 7;
        int y = ty * 16 + (p >> 4), xp = tx * 16 + (p & 15) + 1;
        *(half8*)(img2 + (size_t)y * 4224 + xp * 64 + cc * 8) = *(const half8*)(obuf + p * 72 + cc * 8);
    }
    if (tid < 128)
        atomicAdd(&sums2[(s * 64 + (tid >> 1)) * 2 + (tid & 1)], statsl[tid]);
}

// ======== conv3 (R6/R9 version): 64x4 tile, 512 thr, phase-split stage, f16 output ========
__global__ __launch_bounds__(512, 4) void conv3_k(
    const half_t* __restrict__ h2p, const half_t* __restrict__ zr2,
    const half_t* __restrict__ wt3, const float* __restrict__ b3,
    const half_t* __restrict__ th2, half_t* __restrict__ h3,
    float* __restrict__ sums3)
{
    __shared__ __align__(16) char smem[51200];  // 6 row-slots * 8448 = 50688 + statsl
    float* statsl = (float*)(smem + 50688);
    const int ty = blockIdx.x, s = blockIdx.y, n = blockIdx.z;
    const int tid = threadIdx.x;
    const int l = tid & 63, w = tid >> 6, l15 = l & 15, g = l >> 4;
    const int wy = w & 3, och = w >> 2;
    const int ty4 = ty * 4;
    if (tid < 128) statsl[tid] = 0.f;

    const half_t* img = h2p + (size_t)(n * NS + s) * 270336;
    const half_t* zrow = zr2 + s * 4224;
    const half_t* wb = wt3 + (size_t)s * 36864;
    const int j = tid & 7;
    const half8 tshj = *(const half8*)(th2 + s * 64 + j * 8);

    // ---- A-stage issue: rows ty4-1..ty4+2 -> slots 0..3 ----
    half8 sa0, sa1, sa2, sa3, sa4; int aa0, aa1, aa2, aa3, aa4;
#define PREPA(K, ST, SL) { int idx = tid + K * 512; int p = idx >> 3; int rr = p / 66; \
    int col = p - rr * 66; int row = ty4 - 1 + rr; bool ok = idx < 2112; \
    const half_t* rp = ((unsigned)row < 64u) ? (img + (size_t)row * 4224) : zrow; \
    ST = *(const half8*)(rp + col * 64 + j * 8); \
    SL = ok ? (rr * 8448 + col * 128 + ((j * 16) ^ ((col & 7) << 4))) : -1; }
    PREPA(0, sa0, aa0)
    PREPA(1, sa1, aa1)
    PREPA(2, sa2, aa2)
    PREPA(3, sa3, aa3)
    PREPA(4, sa4, aa4)
#undef PREPA
    // ---- B-stage issue (held across compute-A): rows ty4+3, ty4+4 -> slots 4,5 ----
    half8 sb0, sb1, sb2; int ab0, ab1, ab2;
#define PREPB(K, ST, SL) { int idx = tid + K * 512; int p = idx >> 3; int rr = p / 66; \
    int col = p - rr * 66; int row = ty4 + 3 + rr; bool ok = idx < 1056; \
    const half_t* rp = ((unsigned)row < 64u) ? (img + (size_t)row * 4224) : zrow; \
    ST = *(const half8*)(rp + col * 64 + j * 8); \
    SL = ok ? ((4 + rr) * 8448 + col * 128 + ((j * 16) ^ ((col & 7) << 4))) : -1; }
    PREPB(0, sb0, ab0)
    PREPB(1, sb1, ab1)
    PREPB(2, sb2, ab2)
#undef PREPB
    if (aa0 >= 0) *(half8*)(smem + aa0) = sr8(sa0, tshj);
    if (aa1 >= 0) *(half8*)(smem + aa1) = sr8(sa1, tshj);
    if (aa2 >= 0) *(half8*)(smem + aa2) = sr8(sa2, tshj);
    if (aa3 >= 0) *(half8*)(smem + aa3) = sr8(sa3, tshj);
    if (aa4 >= 0) *(half8*)(smem + aa4) = sr8(sa4, tshj);
    __syncthreads();

    f32x4 acc[4][2];
#pragma unroll
    for (int mt = 0; mt < 4; ++mt)
#pragma unroll
        for (int nt = 0; nt < 2; ++nt) acc[mt][nt] = (f32x4){0.f, 0.f, 0.f, 0.f};

    // 18-step (kc,tap) chain: A = taps 0..2 x kc0,kc1 ; B = taps 3..8 x kc0,kc1
    const int UT[19] = {0,1,2,0,1,2, 3,4,5,6,7,8, 3,4,5,6,7,8, 0};
    const int UK[19] = {0,0,0,1,1,1, 0,0,0,0,0,0, 1,1,1,1,1,1, 0};
    half8 bfa[2], bfb[2];
#define LW3(BF, U) { \
    BF[0] = *(const half8*)(wb + (UT[U] * 64 + och * 32 + l15) * 64 + UK[U] * 32 + g * 8); \
    BF[1] = *(const half8*)(wb + (UT[U] * 64 + och * 32 + 16 + l15) * 64 + UK[U] * 32 + g * 8); }
    LW3(bfa, 0)
#define CSTEP3(BF, U) { \
    int tap_ = UT[U]; int ky_ = tap_ / 3, kx_ = tap_ - ky_ * 3; \
    const char* rp_ = smem + (wy + ky_) * 8448; \
    _Pragma("unroll") \
    for (int mt = 0; mt < 4; ++mt) { \
        int px = mt * 16 + l15 + kx_; \
        int sw = (px & 7) << 4; \
        half8 a_ = *(const half8*)(rp_ + px * 128 + ((UK[U] * 64 + g * 16) ^ sw)); \
        acc[mt][0] = __builtin_amdgcn_mfma_f32_16x16x32_f16(a_, BF[0], acc[mt][0], 0, 0, 0); \
        acc[mt][1] = __builtin_amdgcn_mfma_f32_16x16x32_f16(a_, BF[1], acc[mt][1], 0, 0, 0); \
    } }

    // phase A: steps 0..5 (ky=0)
    LW3(bfb, 1)  CSTEP3(bfa, 0)
    LW3(bfa, 2)  CSTEP3(bfb, 1)
    LW3(bfb, 3)  CSTEP3(bfa, 2)
    LW3(bfa, 4)  CSTEP3(bfb, 3)
    LW3(bfb, 5)  CSTEP3(bfa, 4)
    LW3(bfa, 6)  CSTEP3(bfb, 5)
    // write B rows (slots 4,5 — untouched by phase A)
    if (ab0 >= 0) *(half8*)(smem + ab0) = sr8(sb0, tshj);
    if (ab1 >= 0) *(half8*)(smem + ab1) = sr8(sb1, tshj);
    if (ab2 >= 0) *(half8*)(smem + ab2) = sr8(sb2, tshj);
    __syncthreads();
    // phase B: steps 6..17
    LW3(bfb, 7)   CSTEP3(bfa, 6)
    LW3(bfa, 8)   CSTEP3(bfb, 7)
    LW3(bfb, 9)   CSTEP3(bfa, 8)
    LW3(bfa, 10)  CSTEP3(bfb, 9)
    LW3(bfb, 11)  CSTEP3(bfa, 10)
    LW3(bfa, 12)  CSTEP3(bfb, 11)
    LW3(bfb, 13)  CSTEP3(bfa, 12)
    LW3(bfa, 14)  CSTEP3(bfb, 13)
    LW3(bfb, 15)  CSTEP3(bfa, 14)
    LW3(bfa, 16)  CSTEP3(bfb, 15)
    LW3(bfb, 17)  CSTEP3(bfa, 16)
                  CSTEP3(bfb, 17)
#undef CSTEP3
#undef LW3

    // ---- epilogue: bias + register stats + coalesced f16 store (pre-BN3) ----
    float bias0 = b3[s * 64 + och * 32 + l15];
    float bias1 = b3[s * 64 + och * 32 + 16 + l15];
    float s10 = 0.f, s20 = 0.f, s11 = 0.f, s21 = 0.f;
    const int gy = ty4 + wy;
    half_t* hb = h3 + (size_t)((s * NN + n) * 64) * 4096;
#pragma unroll
    for (int mt = 0; mt < 4; ++mt)
#pragma unroll
        for (int nt = 0; nt < 2; ++nt) {
            int c = och * 32 + nt * 16 + l15;
            float bias = nt ? bias1 : bias0;
            half4 hv;
#pragma unroll
            for (int r = 0; r < 4; ++r) {
                float vv = acc[mt][nt][r] + bias;
                hv[r] = (half_t)vv;
                if (nt) { s11 += vv; s21 += vv * vv; } else { s10 += vv; s20 += vv * vv; }
            }
            *(half4*)(hb + (size_t)c * 4096 + gy * 64 + mt * 16 + g * 4) = hv;
        }

    s10 += __shfl_xor(s10, 16); s10 += __shfl_xor(s10, 32);
    s20 += __shfl_xor(s20, 16); s20 += __shfl_xor(s20, 32);
    s11 += __shfl_xor(s11, 16); s11 += __shfl_xor(s11, 32);
    s21 += __shfl_xor(s21, 16); s21 += __shfl_xor(s21, 32);
    if (l < 16) {
        atomicAdd(&statsl[(och * 32 + l15) * 2], s10);
        atomicAdd(&statsl[(och * 32 + l15) * 2 + 1], s20);
        atomicAdd(&statsl[(och * 32 + 16 + l15) * 2], s11);
        atomicAdd(&statsl[(och * 32 + 16 + l15) * 2 + 1], s21);
    }
    __syncthreads();
    if (tid < 128)
        atomicAdd(&sums3[(s * 64 + (tid >> 1)) * 2 + (tid & 1)], statsl[tid]);
}

// -------- final: read f16 pre-BN3, apply BN3+ReLU, write fp32 d_out (grid-stride) --------
__global__ __launch_bounds__(256) void final_k(float* __restrict__ out,
                                               const half_t* __restrict__ h3,
                                               const float* __restrict__ a3,
                                               const float* __restrict__ b3p)
{
    const size_t stride = (size_t)gridDim.x * 256;
    for (size_t i = (size_t)blockIdx.x * 256 + threadIdx.x; i < 33554432ull; i += stride) {
        size_t e = i * 4;
        int ch = (int)((e >> 12) & 63) + (int)(e >> 23) * 64; // c + s*64
        float sc = a3[ch], sh = b3p[ch];
        half4 hv = *(const half4*)(h3 + e);
        f32x4 v;
#pragma unroll
        for (int r = 0; r < 4; ++r) v[r] = fmaxf(fmaf(sc, (float)hv[r], sh), 0.f);
        *(f32x4*)(out + e) = v;
    }
}

extern "C" void kernel_launch(void* const* d_in, const int* in_sizes, int n_in,
                              void* d_out, int out_size, void* d_ws, size_t ws_size,
                              hipStream_t stream)
{
    const float* x   = (const float*)d_in[0];
    const float* w1  = (const float*)d_in[1];
    const float* b1  = (const float*)d_in[2];
    const float* g1  = (const float*)d_in[3];
    const float* be1 = (const float*)d_in[4];
    const float* w2  = (const float*)d_in[5];
    const float* b2  = (const float*)d_in[6];
    const float* g2  = (const float*)d_in[7];
    const float* be2 = (const float*)d_in[8];
    const float* w3  = (const float*)d_in[9];
    const float* b3  = (const float*)d_in[10];
    const float* g3  = (const float*)d_in[11];
    const float* be3 = (const float*)d_in[12];

    char* ws = (char*)d_ws;
    half_t* h1p = (half_t*)(ws + OFF_H1P);
    half_t* h2p = (half_t*)d_out;              // h2 lives in d_out (277MB <= 512MB)
    half_t* h3  = (half_t*)(ws + OFF_H3);      // f16 pre-BN3 output
    half_t* zr1 = (half_t*)(ws + OFF_ZR1);
    half_t* zr2 = (half_t*)(ws + OFF_ZR2);
    float*  wt1 = (float*)(ws + OFF_WT1);
    half_t* wt2 = (half_t*)(ws + OFF_WT2);
    half_t* wt3 = (half_t*)(ws + OFF_WT3);
    float*  sums = (float*)(ws + OFF_SUMS);
    float *s1v = sums, *s2v = sums + 1024, *s3v = sums + 3072;
    float*  prm = (float*)(ws + OFF_PRM);
    float *a1 = prm,        *b1p = prm + 512,  *t1 = prm + 1024;
    float *a2 = prm + 1536, *b2p = prm + 2560, *t2 = prm + 3584;
    float *a3 = prm + 4608, *b3p = prm + 5632, *t3 = prm + 6656;
    half_t* th = (half_t*)(ws + OFF_TH);
    half_t *th1 = th, *th2 = th + 512, *th3 = th + 1536;
    float* out = (float*)d_out;

    hipMemsetAsync(ws + OFF_SUMS, 0, 20480, stream);
    transform1_k<<<54, 256, 0, stream>>>(w1, wt1);
    dim3 grid1(16, 16, 32); // (tile, seed, sample)
    conv1_k<<<grid1, 256, 0, stream>>>(x, wt1, b1, h1p, s1v);
    bnparam_k<<<2, 256, 0, stream>>>(s1v, g1, be1, a1, b1p, t1, th1, 512);
    padfill_k<<<1041, 256, 0, stream>>>(h1p, zr1, t1, 32, 2, 135168L, 2112, 262144L, 266368L);
    wtrans2_k<<<1152, 256, 0, stream>>>(w2, a1, wt2);
    conv2_k<<<grid1, 256, 0, stream>>>(h1p, zr1, wt2, b2, th1, h2p, s2v);
    bnparam_k<<<4, 256, 0, stream>>>(s2v, g2, be2, a2, b2p, t2, th2, 1024);
    padfill_k<<<2081, 256, 0, stream>>>(h2p, zr2, t2, 64, 3, 270336L, 4224, 524288L, 532736L);
    wtrans3_k<<<2304, 256, 0, stream>>>(w3, a2, wt3);
    dim3 grid3(16, 16, 32); // (y-tile, seed, sample)
    conv3_k<<<grid3, 512, 0, stream>>>(h2p, zr2, wt3, b3, th2, h3, s3v);
    bnparam_k<<<4, 256, 0, stream>>>(s3v, g3, be3, a3, b3p, t3, th3, 1024);
    final_k<<<4096, 256, 0, stream>>>(out, h3, a3, b3p);
}